// Round 9
// baseline (181.516 us; speedup 1.0000x reference)
//
#include <hip/hip_runtime.h>
#include <math.h>

#define N 8192
#define D 128
#define NC 256
#define NT 64                    // 128-wide tiles per dim
#define NBLK (NT * (NT + 1) / 2) // 2080

typedef __attribute__((ext_vector_type(8))) short bf8;   // 8 bf16 = 4 VGPRs
typedef __attribute__((ext_vector_type(4))) float f4;    // MFMA acc

__device__ __forceinline__ unsigned short bf16_rtne(float f) {
    unsigned u = __float_as_uint(f);
    u += 0x7FFF + ((u >> 16) & 1);
    return (unsigned short)(u >> 16);
}
__device__ __forceinline__ float bf16_tof(unsigned short h) {
    return __uint_as_float((unsigned)h << 16);
}

// async global->LDS DMA, 16 B per lane (global_load_lds_dwordx4).
// Requirement (HW): LDS dst = wave-uniform base + lane*16 — our staging
// index map satisfies this exactly (cc consecutive per wave).
__device__ __forceinline__ void async_cp16(const void* g, void* l) {
    __builtin_amdgcn_global_load_lds(
        (const __attribute__((address_space(1))) unsigned*)g,
        (__attribute__((address_space(3))) unsigned*)l, 16, 0, 0);
}

// ---------------------------------------------------------------------------
// Kernel 1: normalize + 3-limb bf16 split (row-major), sq, histogram,
// best-pack init. n = x/||x||; n = h1+h2+h3 + O(2^-24).
// ---------------------------------------------------------------------------
__global__ __launch_bounds__(256) void prep_kernel(
    const float* __restrict__ x, const int* __restrict__ labels,
    short* __restrict__ H,       // 3 limb matrices, H + l*N*D
    float* __restrict__ sq, int* __restrict__ hist,
    unsigned long long* __restrict__ pos_pack,
    unsigned long long* __restrict__ neg_pack) {
    __shared__ float Xs[64 * 129];
    const int t = threadIdx.x;
    const int r0 = blockIdx.x * 64;

    {   // init best-packs: 128 blocks x 256 threads cover 8192
        const int g = blockIdx.x * 256 + t;
        if (g < N) { pos_pack[g] = 0ULL; neg_pack[g] = ~0ULL; }
    }

    // load 64x128 block
#pragma unroll
    for (int p = 0; p < 8; ++p) {
        const int lin = p * 256 + t;
        const int row = lin >> 5;
        const int c0 = (lin & 31) << 2;
        const float4 v = *(const float4*)(x + (size_t)(r0 + row) * D + c0);
        float* dst = &Xs[row * 129 + c0];
        dst[0] = v.x; dst[1] = v.y; dst[2] = v.z; dst[3] = v.w;
    }
    __syncthreads();

    // 4 threads/row: norm; normalize in place (exclusive 32-elem segment);
    // sq of normalized; limb emission.
    const int r = t >> 2, q2 = t & 3;
    float* src = &Xs[r * 129 + q2 * 32];
    float s = 0.f;
#pragma unroll
    for (int i = 0; i < 32; ++i) s = fmaf(src[i], src[i], s);
    s += __shfl_xor(s, 1, 64);
    s += __shfl_xor(s, 2, 64);
    const float nrm = sqrtf(s);
    float t2 = 0.f;
#pragma unroll
    for (int i = 0; i < 32; ++i) {
        const float n = src[i] / nrm;
        src[i] = n;
        t2 = fmaf(n, n, t2);
    }
    t2 += __shfl_xor(t2, 1, 64);
    t2 += __shfl_xor(t2, 2, 64);
    if (q2 == 0) sq[r0 + r] = t2;

    // limb split, 8B-coalesced stores
    const size_t gbase = (size_t)(r0 + r) * D + q2 * 32;
#pragma unroll
    for (int g = 0; g < 8; ++g) {
        short4 o1, o2, o3;
        short* p1 = (short*)&o1; short* p2 = (short*)&o2; short* p3 = (short*)&o3;
#pragma unroll
        for (int i = 0; i < 4; ++i) {
            const float n = src[g * 4 + i];
            const unsigned short h1 = bf16_rtne(n);
            const float r1 = n - bf16_tof(h1);
            const unsigned short h2 = bf16_rtne(r1);
            const float r2 = r1 - bf16_tof(h2);
            const unsigned short h3 = bf16_rtne(r2);
            p1[i] = (short)h1; p2[i] = (short)h2; p3[i] = (short)h3;
        }
        *(short4*)(H + gbase + g * 4)                     = o1;
        *(short4*)(H + (size_t)N * D + gbase + g * 4)     = o2;
        *(short4*)(H + (size_t)2 * N * D + gbase + g * 4) = o3;
    }

    if (t < 64) atomicAdd(&hist[labels[r0 + t]], 1);
}

// ---------------------------------------------------------------------------
// Kernel 2: symmetric 128x128-tile Gram via 3-limb bf16 MFMA (6 limb-pair
// products), fused arg-reductions. Staging via global_load_lds (async DMA,
// no VGPR round-trip) — R9 change; layouts/epilogue identical to R8.
// ---------------------------------------------------------------------------
__device__ __forceinline__ unsigned int fbits(float f) {
    union { float f; unsigned int u; } x; x.f = f; return x.u;
}
__device__ __forceinline__ unsigned long long pack_pos(float v, int j) {
    return ((unsigned long long)fbits(v) << 32) | (unsigned int)(8191 - j);
}
__device__ __forceinline__ unsigned long long pack_neg(float v, int j) {
    return ((unsigned long long)fbits(v) << 32) | (unsigned int)j;
}
__device__ __forceinline__ void red_max(float& v, int& j, int mask) {
    const float ov = __shfl_xor(v, mask, 64);
    const int   oj = __shfl_xor(j, mask, 64);
    if (ov > v || (ov == v && oj < j)) { v = ov; j = oj; }
}
__device__ __forceinline__ void red_min(float& v, int& j, int mask) {
    const float ov = __shfl_xor(v, mask, 64);
    const int   oj = __shfl_xor(j, mask, 64);
    if (ov < v || (ov == v && oj < j)) { v = ov; j = oj; }
}

__global__ __launch_bounds__(256) void miner_kernel(
    const short* __restrict__ H, const float* __restrict__ sq,
    const int* __restrict__ labels,
    unsigned long long* __restrict__ pos_pack,
    unsigned long long* __restrict__ neg_pack) {
    __shared__ __align__(16) short sA[3 * 128 * 32];  // 24 KB; reused as u64 scratch
    __shared__ __align__(16) short sB[3 * 128 * 32];  // 24 KB
    __shared__ float sqI[128], sqJ[128];
    __shared__ int   lbI[128], lbJ[128];

    const int t = threadIdx.x;
    const int w = t >> 6;       // wave id: rows w*32..w*32+31
    const int l = t & 63;
    const int quad = l >> 4;
    const int l16 = l & 15;

    // decode upper-triangular (bi, bj), bi <= bj, NT=64
    const int b = blockIdx.x;
    int bi = (int)((129.0f - sqrtf(16641.0f - 8.0f * (float)b)) * 0.5f);
    while (bi > 0 && (bi * NT - bi * (bi - 1) / 2) > b) --bi;
    while (((bi + 1) * NT - (bi + 1) * bi / 2) <= b) ++bi;
    const int bj = bi + (b - (bi * NT - bi * (bi - 1) / 2));
    const int I0 = bi * 128, J0 = bj * 128;
    const bool diag = (bi == bj);

    if (t < 128) { sqI[t] = sq[I0 + t]; lbI[t] = labels[I0 + t]; }
    else         { sqJ[t - 128] = sq[J0 + t - 128]; lbJ[t - 128] = labels[J0 + t - 128]; }

    f4 acc[2][8];
#pragma unroll
    for (int rt = 0; rt < 2; ++rt)
#pragma unroll
        for (int ct = 0; ct < 8; ++ct) acc[rt][ct] = (f4){0.f, 0.f, 0.f, 0.f};

    for (int q = 0; q < 4; ++q) {
        const int kc = q * 32;
        __syncthreads();
        // async stage 48 KB: [limb][sample][32k] bf16 both panels.
        // Per p: all 256 threads cover one contiguous 4 KB run of a single
        // (limb, side) segment; each wave = uniform base + lane*16. The
        // compiler drains vmcnt before the next barrier.
#pragma unroll
        for (int p = 0; p < 12; ++p) {
            const int c = p * 256 + t;          // 0..3071
            const int limb = c >> 10;
            const int rem  = c & 1023;
            const int side = rem >> 9;
            const int cc   = rem & 511;
            const int sample = cc >> 2;
            const int sub    = cc & 3;
            const short* gsrc = H + (size_t)limb * N * D +
                                (size_t)((side ? J0 : I0) + sample) * D + kc + sub * 8;
            short* ldst = (side ? sB : sA) + (limb * 128 + sample) * 32 + sub * 8;
            async_cp16(gsrc, ldst);
        }
        __syncthreads();

        // all 6 A-fragments (3 limbs x 2 row-tiles); wave-contiguous 1KB reads
        bf8 aF[3][2];
#pragma unroll
        for (int limb = 0; limb < 3; ++limb)
#pragma unroll
            for (int rt = 0; rt < 2; ++rt)
                aF[limb][rt] = *(const bf8*)
                    &sA[(limb * 128 + w * 32 + rt * 16 + l16) * 32 + quad * 8];

#pragma unroll
        for (int lb = 0; lb < 3; ++lb) {
            bf8 bF[8];
#pragma unroll
            for (int ct = 0; ct < 8; ++ct)
                bF[ct] = *(const bf8*)
                    &sB[(lb * 128 + ct * 16 + l16) * 32 + quad * 8];
#pragma unroll
            for (int la = 0; la + lb < 3; ++la)      // limb pairs la+lb <= 2
#pragma unroll
                for (int rt = 0; rt < 2; ++rt)
#pragma unroll
                    for (int ct = 0; ct < 8; ++ct)
                        acc[rt][ct] = __builtin_amdgcn_mfma_f32_16x16x32_bf16(
                            aF[la][rt], bF[ct], acc[rt][ct], 0, 0, 0);
        }
    }

    // ---- epilogue ----
    float sjv[8]; int ljv[8];
#pragma unroll
    for (int ct = 0; ct < 8; ++ct) {
        sjv[ct] = sqJ[ct * 16 + l16];
        ljv[ct] = lbJ[ct * 16 + l16];
    }

    // I-side: rows w*32+rt*16+quad*4+r; candidates over ct then l16-lanes
#pragma unroll
    for (int rt = 0; rt < 2; ++rt)
#pragma unroll
        for (int r = 0; r < 4; ++r) {
            const int lr = w * 32 + rt * 16 + quad * 4 + r;
            const float si = sqI[lr];
            const int   liv = lbI[lr];
            const int   grow = I0 + lr;
            float bpv = -1.0f, bnv = INFINITY; int bpj = 0, bnj = 0;
#pragma unroll
            for (int ct = 0; ct < 8; ++ct) {
                const float d2 = fmaxf(si + sjv[ct] - 2.0f * acc[rt][ct][r], 0.0f);
                const int col = J0 + ct * 16 + l16;
                const bool same = (liv == ljv[ct]);
                const float vp = (same && grow != col) ? d2 : 0.0f;
                if (vp > bpv) { bpv = vp; bpj = col; }
                const float vn = same ? INFINITY : d2;
                if (vn < bnv) { bnv = vn; bnj = col; }
            }
            red_max(bpv, bpj, 1); red_max(bpv, bpj, 2);
            red_max(bpv, bpj, 4); red_max(bpv, bpj, 8);
            red_min(bnv, bnj, 1); red_min(bnv, bnj, 2);
            red_min(bnv, bnj, 4); red_min(bnv, bnj, 8);
            if (l16 == 0) {
                atomicMax(&pos_pack[grow], pack_pos(bpv, bpj));
                atomicMin(&neg_pack[grow], pack_neg(bnv, bnj));
            }
        }

    // J-side (skip on diagonal): per-col best over this wave's 32 rows,
    // reduce over quad (masks 16,32), cross-wave merge via LDS, commit.
    if (!diag) {
        float bpv[8], bnv[8]; int bpj[8], bnj[8];
#pragma unroll
        for (int ct = 0; ct < 8; ++ct) {
            bpv[ct] = -1.0f; bpj[ct] = 0; bnv[ct] = INFINITY; bnj[ct] = 0;
#pragma unroll
            for (int rt = 0; rt < 2; ++rt)
#pragma unroll
                for (int r = 0; r < 4; ++r) {
                    const int lr = w * 32 + rt * 16 + quad * 4 + r;
                    const float d2 =
                        fmaxf(sqI[lr] + sjv[ct] - 2.0f * acc[rt][ct][r], 0.0f);
                    const int row = I0 + lr;
                    const bool same = (lbI[lr] == ljv[ct]);  // no self off-diag
                    const float vp = same ? d2 : 0.0f;
                    if (vp > bpv[ct]) { bpv[ct] = vp; bpj[ct] = row; }
                    const float vn = same ? INFINITY : d2;
                    if (vn < bnv[ct]) { bnv[ct] = vn; bnj[ct] = row; }
                }
#pragma unroll
            for (int m = 16; m < 64; m <<= 1) {
                red_max(bpv[ct], bpj[ct], m);
                red_min(bnv[ct], bnj[ct], m);
            }
        }
        unsigned long long* scr = (unsigned long long*)sA;  // 8 KB scratch
        __syncthreads();
        if (quad == 0) {
#pragma unroll
            for (int ct = 0; ct < 8; ++ct) {
                scr[w * 128 + ct * 16 + l16]       = pack_pos(bpv[ct], bpj[ct]);
                scr[512 + w * 128 + ct * 16 + l16] = pack_neg(bnv[ct], bnj[ct]);
            }
        }
        __syncthreads();
        if (t < 128) {
            unsigned long long mp = 0ULL, mn = ~0ULL;
#pragma unroll
            for (int ww = 0; ww < 4; ++ww) {
                const unsigned long long p = scr[ww * 128 + t];
                const unsigned long long qq = scr[512 + ww * 128 + t];
                if (p > mp) mp = p;
                if (qq < mn) mn = qq;
            }
            atomicMax(&pos_pack[J0 + t], mp);
            atomicMin(&neg_pack[J0 + t], mn);
        }
    }
}

// ---------------------------------------------------------------------------
// Kernel 3: finalize -> int32 outputs [anchor | pos | neg | keep]
// ---------------------------------------------------------------------------
__global__ void finalize_kernel(const unsigned long long* __restrict__ pos_pack,
                                const unsigned long long* __restrict__ neg_pack,
                                const int* __restrict__ labels,
                                const int* __restrict__ hist,
                                int* __restrict__ out) {
    const int r = blockIdx.x * 256 + threadIdx.x;
    out[r]         = r;
    out[N + r]     = 8191 - (int)(pos_pack[r] & 0xFFFFFFFFULL);
    out[2 * N + r] = (int)(neg_pack[r] & 0xFFFFFFFFULL);
    const int cnt = hist[labels[r]];
    out[3 * N + r] = (cnt >= 2 && cnt < N) ? 1 : 0;
}

extern "C" void kernel_launch(void* const* d_in, const int* in_sizes, int n_in,
                              void* d_out, int out_size, void* d_ws, size_t ws_size,
                              hipStream_t stream) {
    const float* x      = (const float*)d_in[0];
    const int*   labels = (const int*)d_in[1];
    int* out = (int*)d_out;

    short* H = (short*)d_ws;                                // 3*N*D bf16 = 6 MB
    float* sq = (float*)(H + (size_t)3 * N * D);            // N floats
    unsigned long long* pos_pack =
        (unsigned long long*)(sq + N);                      // N u64
    int* hist = (int*)(pos_pack + N);                       // NC ints
    unsigned long long* neg_pack =
        (unsigned long long*)(hist + NC);                   // N u64

    hipMemsetAsync(hist, 0, NC * 4, stream);
    prep_kernel<<<N / 64, 256, 0, stream>>>(x, labels, H, sq, hist,
                                            pos_pack, neg_pack);
    miner_kernel<<<NBLK, 256, 0, stream>>>(H, sq, labels, pos_pack, neg_pack);
    finalize_kernel<<<N / 256, 256, 0, stream>>>(pos_pack, neg_pack, labels, hist, out);
}